// Round 1
// baseline (169.899 us; speedup 1.0000x reference)
//
#include <hip/hip_runtime.h>
#include <hip/hip_bf16.h>

// ---------------- problem constants ----------------
#define T_LEN   1048576
#define FL      1024
#define PAD     512
#define HOP     256
#define NFR     4097          // frames per batch = T/HOP + 1
#define FT      4224          // frames padded to 33*128
#define XPLEN   1082112       // (FT-1)*HOP + FL  -> padded xp length per batch
#define M_OUT   1026
#define M_PAD   1152          // 9*128
#define NBATCH  8

typedef __bf16 bf16x8 __attribute__((ext_vector_type(8)));
typedef float  f32x4  __attribute__((ext_vector_type(4)));

__device__ __forceinline__ void gload_lds16(const void* g, void* l) {
  __builtin_amdgcn_global_load_lds(
      (const __attribute__((address_space(1))) unsigned int*)g,
      (__attribute__((address_space(3))) unsigned int*)l, 16, 0, 0);
}

// ---------------- prep: reflect-pad x and convert to bf16 ----------------
__global__ __launch_bounds__(256) void pad_convert_x(
    const float* __restrict__ x, __hip_bfloat16* __restrict__ xp) {
  int i = blockIdx.x * 256 + threadIdx.x;
  int b = blockIdx.y;
  if (i >= XPLEN) return;
  float v = 0.f;
  if (i < T_LEN + FL) {
    int t = i - PAD;
    int idx = (t < 0) ? -t : ((t >= T_LEN) ? (2 * T_LEN - 2 - t) : t);
    v = x[(size_t)b * T_LEN + idx];
  }
  xp[(size_t)b * XPLEN + i] = __float2bfloat16(v);
}

// ---------------- prep: convert basis to bf16, pad M to 1152 ----------------
__global__ __launch_bounds__(256) void convert_basis(
    const float* __restrict__ basis, __hip_bfloat16* __restrict__ bb) {
  int gid = blockIdx.x * 256 + threadIdx.x;   // over M_PAD*1024
  if (gid >= M_PAD * FL) return;
  int o = gid >> 10;
  float v = (o < M_OUT) ? basis[gid] : 0.f;
  bb[gid] = __float2bfloat16(v);
}

// ---------------- GEMM: C[o, (b,f)] = Basis x Frames ----------------
// 128x128 tile, BK=32, 4 waves (2x2), each wave 64x64 via 4x4 16x16x32 MFMA.
__global__ __launch_bounds__(256) void stft_gemm(
    const __hip_bfloat16* __restrict__ basisBf,   // [M_PAD][1024]
    const __hip_bfloat16* __restrict__ xpBf,      // [NBATCH][XPLEN]
    float* __restrict__ out) {                    // [NBATCH][M_OUT][NFR]
  __shared__ __hip_bfloat16 As[128 * 32];
  __shared__ __hip_bfloat16 Bs[128 * 32];

  const int tid = threadIdx.x;
  const int w = tid >> 6;
  const int l = tid & 63;
  const int tileM = blockIdx.x * 128;
  const int tileN = blockIdx.y * 128;
  const int b = blockIdx.z;
  const __hip_bfloat16* __restrict__ xb = xpBf + (size_t)b * XPLEN;

  const int waveM = (w & 1) * 64;
  const int waveN = (w >> 1) * 64;

  // staging geometry: per instr a wave fills 16 rows (1024B); lane l -> row +l/4, col (l&3)*8
  const int sr = l >> 2;
  const int sc = (l & 3) * 8;

  f32x4 acc[4][4] = {};

  const int ar = l & 15;
  const int ak = (l >> 4) * 8;

  for (int k0 = 0; k0 < FL; k0 += 32) {
#pragma unroll
    for (int j = 0; j < 2; ++j) {
      const int rbase = (j * 4 + w) * 16;
      const __hip_bfloat16* srcA =
          basisBf + (size_t)(tileM + rbase + sr) * FL + k0 + sc;
      gload_lds16(srcA, (void*)&As[rbase * 32]);
      const __hip_bfloat16* srcB =
          xb + (size_t)(tileN + rbase + sr) * HOP + k0 + sc;
      gload_lds16(srcB, (void*)&Bs[rbase * 32]);
    }
    __syncthreads();

    bf16x8 a[4], bv[4];
#pragma unroll
    for (int m = 0; m < 4; ++m)
      a[m] = *(const bf16x8*)&As[(waveM + m * 16 + ar) * 32 + ak];
#pragma unroll
    for (int n = 0; n < 4; ++n)
      bv[n] = *(const bf16x8*)&Bs[(waveN + n * 16 + ar) * 32 + ak];

#pragma unroll
    for (int m = 0; m < 4; ++m)
#pragma unroll
      for (int n = 0; n < 4; ++n)
        acc[m][n] = __builtin_amdgcn_mfma_f32_16x16x32_bf16(a[m], bv[n], acc[m][n], 0, 0, 0);
    __syncthreads();
  }

  // store: C/D layout col = lane&15 (frame), row = (lane>>4)*4 + j (bin)
  const int cn = l & 15;
  const int rb = (l >> 4) * 4;
#pragma unroll
  for (int m = 0; m < 4; ++m) {
#pragma unroll
    for (int j = 0; j < 4; ++j) {
      const int o = tileM + waveM + m * 16 + rb + j;
      if (o < M_OUT) {
#pragma unroll
        for (int n = 0; n < 4; ++n) {
          const int f = tileN + waveN + n * 16 + cn;
          if (f < NFR)
            out[((size_t)b * M_OUT + o) * NFR + f] = acc[m][n][j];
        }
      }
    }
  }
}

extern "C" void kernel_launch(void* const* d_in, const int* in_sizes, int n_in,
                              void* d_out, int out_size, void* d_ws, size_t ws_size,
                              hipStream_t stream) {
  const float* x = (const float*)d_in[0];       // [8, 1048576] f32
  const float* basis = (const float*)d_in[1];   // [1026, 1, 1024] f32
  float* out = (float*)d_out;                   // [8, 1026, 4097] f32

  __hip_bfloat16* xpBf = (__hip_bfloat16*)d_ws;                       // 8*XPLEN bf16
  __hip_bfloat16* basisBf = xpBf + (size_t)NBATCH * XPLEN;            // M_PAD*1024 bf16

  dim3 gPad((XPLEN + 255) / 256, NBATCH);
  pad_convert_x<<<gPad, 256, 0, stream>>>(x, xpBf);

  dim3 gBas((M_PAD * FL + 255) / 256);
  convert_basis<<<gBas, 256, 0, stream>>>(basis, basisBf);

  dim3 gGemm(M_PAD / 128, FT / 128, NBATCH);   // 9 x 33 x 8
  stft_gemm<<<gGemm, 256, 0, stream>>>(basisBf, xpBf, out);
}

// Round 2
// 139.807 us; speedup vs baseline: 1.2152x; 1.2152x over previous
//
#include <hip/hip_runtime.h>
#include <hip/hip_bf16.h>

// ---------------- problem constants ----------------
#define T_LEN 1048576
#define FL    1024
#define PADL  512
#define HOP   256
#define NFR   4097            // frames per batch
#define NB    8
#define NTOT  32776           // NB*NFR
#define XP2   1049600         // T_LEN + FL (reflect-padded length per batch)
#define M_OUT 1026
#define M_PAD 1280            // 5*256
#define BM 256
#define BN 256
#define BK 32
#define KT 32                 // FL/BK
#define MT 5
#define NT 129                // ceil(NTOT/256)
#define NWG 645               // MT*NT

typedef __bf16 bf16x8 __attribute__((ext_vector_type(8)));
typedef float  f32x4  __attribute__((ext_vector_type(4)));

__device__ __forceinline__ void gload16(const __hip_bfloat16* g, void* l) {
  __builtin_amdgcn_global_load_lds(
      (const __attribute__((address_space(1))) unsigned int*)g,
      (__attribute__((address_space(3))) unsigned int*)l, 16, 0, 0);
}

// ---------------- prep: reflect-pad x, convert to bf16 ----------------
__global__ __launch_bounds__(256) void pad_convert_x(
    const float* __restrict__ x, __hip_bfloat16* __restrict__ xp) {
  int i = blockIdx.x * 256 + threadIdx.x;
  int b = blockIdx.y;
  if (i >= XP2) return;
  int t = i - PADL;
  int idx = (t < 0) ? -t : ((t >= T_LEN) ? (2 * T_LEN - 2 - t) : t);
  xp[(size_t)b * XP2 + i] = __float2bfloat16(x[(size_t)b * T_LEN + idx]);
}

// ---------------- prep: basis to bf16, pad M to 1280 ----------------
__global__ __launch_bounds__(256) void convert_basis(
    const float* __restrict__ basis, __hip_bfloat16* __restrict__ bb) {
  int gid = blockIdx.x * 256 + threadIdx.x;
  if (gid >= M_PAD * FL) return;
  int o = gid >> 10;
  bb[gid] = __float2bfloat16(o < M_OUT ? basis[gid] : 0.f);
}

// ---------------- GEMM: C[o, fglobal] = Basis x Frames ----------------
// 256x256 tile, BK=32, 4 LDS buffers, 8 waves (2Mx4N), per-wave 128x64.
// Counted vmcnt pipeline (depth 3), swizzled LDS (elem ^= (row&6)<<2).
__global__ __launch_bounds__(512, 2) void stft_gemm(
    const __hip_bfloat16* __restrict__ A,   // [M_PAD][FL]
    const __hip_bfloat16* __restrict__ X,   // [NB][XP2]
    float* __restrict__ out) {              // [NB][M_OUT][NFR]
  __shared__ __hip_bfloat16 As[4][BM * BK];
  __shared__ __hip_bfloat16 Bs[4][BN * BK];

  // bijective XCD swizzle (NWG % 8 != 0)
  const int orig = blockIdx.x;
  const int xcd = orig & 7, lin = orig >> 3;
  const int qq = NWG >> 3, rr = NWG & 7;
  const int wg = (xcd < rr ? xcd * (qq + 1) : rr * (qq + 1) + (xcd - rr) * qq) + lin;
  const int mtile = wg % MT, ntile = wg / MT;
  const int tileM = mtile * BM, tileN = ntile * BN;

  const int tid = threadIdx.x;
  const int w = tid >> 6, l = tid & 63;
  const int wm = w >> 2, wn = w & 3;

  // ---- staging addressing (pre-swizzled global source, linear LDS dest) ----
  // instruction j of wave w covers rows (2w+j)*16 .. +15; lane -> row +(l>>2), slot l&3
  const int gslot = (l & 3) ^ ((l >> 3) & 3);   // inverse swizzle on source
  const int srow0 = w * 32 + (l >> 2);
  const int srow1 = srow0 + 16;

  const __hip_bfloat16* aSrc0 = A + (size_t)(tileM + srow0) * FL + gslot * 8;
  const __hip_bfloat16* aSrc1 = A + (size_t)(tileM + srow1) * FL + gslot * 8;

  int fg0 = tileN + srow0;
  size_t bb0 = 0;
  if (fg0 < NTOT) { int b = fg0 / NFR; bb0 = (size_t)b * XP2 + (size_t)(fg0 - b * NFR) * HOP; }
  int fg1 = tileN + srow1;
  size_t bb1 = 0;
  if (fg1 < NTOT) { int b = fg1 / NFR; bb1 = (size_t)b * XP2 + (size_t)(fg1 - b * NFR) * HOP; }
  const __hip_bfloat16* bSrc0 = X + bb0 + gslot * 8;
  const __hip_bfloat16* bSrc1 = X + bb1 + gslot * 8;

  const int ldsO0 = (w * 2 + 0) * 512;   // (2w+j)*16 rows * 32 cols
  const int ldsO1 = (w * 2 + 1) * 512;

  // ---- fragment read addressing (swizzled) ----
  const int swz = (((l >> 4) * 8) ^ ((l & 6) << 2));
  const int aIdx = (wm * 128 + (l & 15)) * BK + swz;
  const int bIdx = (wn * 64 + (l & 15)) * BK + swz;

  f32x4 acc[8][4] = {};

#define STAGE(t_) do {                                        \
    const int qs_ = (t_) & 3; const int ko_ = (t_) * BK;      \
    gload16(aSrc0 + ko_, (void*)&As[qs_][ldsO0]);             \
    gload16(aSrc1 + ko_, (void*)&As[qs_][ldsO1]);             \
    gload16(bSrc0 + ko_, (void*)&Bs[qs_][ldsO0]);             \
    gload16(bSrc1 + ko_, (void*)&Bs[qs_][ldsO1]);             \
  } while (0)

#define ITER(t_, VM_, STG_) do {                                            \
    asm volatile("s_waitcnt vmcnt(" #VM_ ")" ::: "memory");                 \
    __builtin_amdgcn_sched_barrier(0);                                      \
    __builtin_amdgcn_s_barrier();                                           \
    if (STG_) STAGE((t_) + 3);                                              \
    const int q_ = (t_) & 3;                                                \
    bf16x8 af[8], bfr[4];                                                   \
    _Pragma("unroll") for (int m = 0; m < 8; ++m)                           \
      af[m] = *(const bf16x8*)&As[q_][aIdx + m * 512];                      \
    _Pragma("unroll") for (int n = 0; n < 4; ++n)                           \
      bfr[n] = *(const bf16x8*)&Bs[q_][bIdx + n * 512];                     \
    __builtin_amdgcn_s_setprio(1);                                          \
    _Pragma("unroll") for (int m = 0; m < 8; ++m)                           \
      _Pragma("unroll") for (int n = 0; n < 4; ++n)                         \
        acc[m][n] = __builtin_amdgcn_mfma_f32_16x16x32_bf16(                \
            af[m], bfr[n], acc[m][n], 0, 0, 0);                             \
    __builtin_amdgcn_s_setprio(0);                                          \
  } while (0)

  STAGE(0); STAGE(1); STAGE(2);
  for (int t = 0; t < KT - 3; ++t) ITER(t, 8, true);
  ITER(KT - 3, 8, false);
  ITER(KT - 2, 4, false);
  ITER(KT - 1, 0, false);

#undef ITER
#undef STAGE

  // ---- epilogue: C/D layout col = lane&15, row = (lane>>4)*4 + j ----
  const int cn = l & 15, rb = (l >> 4) * 4;
  size_t obase[4];
  bool vn[4];
#pragma unroll
  for (int n = 0; n < 4; ++n) {
    int fg = tileN + wn * 64 + n * 16 + cn;
    vn[n] = fg < NTOT;
    int b = vn[n] ? fg / NFR : 0;
    int fb = fg - b * NFR;
    obase[n] = (size_t)b * M_OUT * NFR + fb;
  }
#pragma unroll
  for (int m = 0; m < 8; ++m) {
    const int o0 = tileM + wm * 128 + m * 16 + rb;
#pragma unroll
    for (int j = 0; j < 4; ++j) {
      const int o = o0 + j;
      if (o < M_OUT) {
#pragma unroll
        for (int n = 0; n < 4; ++n)
          if (vn[n]) out[obase[n] + (size_t)o * NFR] = acc[m][n][j];
      }
    }
  }
}

extern "C" void kernel_launch(void* const* d_in, const int* in_sizes, int n_in,
                              void* d_out, int out_size, void* d_ws, size_t ws_size,
                              hipStream_t stream) {
  const float* x = (const float*)d_in[0];       // [8, 1048576] f32
  const float* basis = (const float*)d_in[1];   // [1026, 1, 1024] f32
  float* out = (float*)d_out;                   // [8, 1026, 4097] f32

  __hip_bfloat16* xpBf = (__hip_bfloat16*)d_ws;                 // NB*XP2 bf16
  __hip_bfloat16* basisBf = xpBf + (size_t)NB * XP2;            // M_PAD*FL bf16

  dim3 gPad((XP2 + 255) / 256, NB);
  pad_convert_x<<<gPad, 256, 0, stream>>>(x, xpBf);

  dim3 gBas((M_PAD * FL + 255) / 256);
  convert_basis<<<gBas, 256, 0, stream>>>(basis, basisBf);

  stft_gemm<<<NWG, 512, 0, stream>>>(basisBf, xpBf, out);
}